// Round 11
// baseline (165.539 us; speedup 1.0000x reference)
//
#include <hip/hip_runtime.h>
#include <stdint.h>

// jax_threefry_partitionable=True: 32-bit random bits are (out0 ^ out1) of
// threefry2x32(key, (hi32(i)=0, lo32(i)=i)), key = (0, 42).
// Ordering note: JAX's normal = erfinv(uniform(mantissa)) is strictly
// monotone in the 23 mantissa bits, so top-k order == mantissa order with
// lower-index tie-break. Verified passing rounds 2/4/6/10 (absmax 0.0112
// vs threshold 0.0844 = fp32 sum-order noise).
constexpr int BF   = 96;    // B * MAX_FRAMES
constexpr int NS   = 500;   // NUM_SAMPLES
constexpr int DSP  = 196;   // N - 1 spatial tokens
constexpr int KSEL = 49;    // TOPK
constexpr int NTOK = 197;   // N
constexpr int DIM  = 512;   // D
constexpr int ROWSTRIDE = 64;   // padded byte stride of one sample's idx row

__device__ __forceinline__ uint32_t rotl32(uint32_t x, int r) {
  // single v_alignbit_b32: rotl(x,r) = rotr(x,32-r)
  return __builtin_amdgcn_alignbit(x, x, 32 - r);
}

__device__ __forceinline__ void threefry2x32(uint32_t x0, uint32_t x1,
                                             uint32_t& o0, uint32_t& o1) {
  const uint32_t ks0 = 0u, ks1 = 42u, ks2 = 0u ^ 42u ^ 0x1BD11BDAu;
  x0 += ks0; x1 += ks1;
#define TF_R(r) { x0 += x1; x1 = rotl32(x1, (r)); x1 ^= x0; }
  TF_R(13) TF_R(15) TF_R(26) TF_R(6)   x0 += ks1; x1 += ks2 + 1u;
  TF_R(17) TF_R(29) TF_R(16) TF_R(24)  x0 += ks2; x1 += ks0 + 2u;
  TF_R(13) TF_R(15) TF_R(26) TF_R(6)   x0 += ks0; x1 += ks1 + 3u;
  TF_R(17) TF_R(29) TF_R(16) TF_R(24)  x0 += ks1; x1 += ks2 + 4u;
  TF_R(13) TF_R(15) TF_R(26) TF_R(6)   x0 += ks2; x1 += ks0 + 5u;
#undef TF_R
  o0 = x0; o1 = x1;
}

__device__ __forceinline__ uint32_t noise_bits(uint32_t p) {
  uint32_t o0, o1;
  threefry2x32(0u, p, o0, o1);
  return o0 ^ o1;
}

// One wave per (b, sample): top-49 of 196 mantissas (23-bit search; ties ->
// lowest index), write the 49 SORTED selected indices as bytes.
__global__ __launch_bounds__(256)
void topk_idx_kernel(uint8_t* __restrict__ idxbuf) {
  const int lane = threadIdx.x & 63;
  const int wid  = (blockIdx.x << 2) | (threadIdx.x >> 6);
  const uint32_t rowbase = (uint32_t)wid * (uint32_t)DSP;

  uint32_t m[4];
#pragma unroll
  for (int g = 0; g < 4; ++g) {
    const int j = (g << 6) | lane;
    uint32_t v = 0u;
    if (j < DSP) v = noise_bits(rowbase + (uint32_t)j) >> 9;  // 23-bit mantissa
    m[g] = v;
  }

  // Largest T with count(m >= T) >= 49. cand >= 1 so padding (m=0) never counts.
  uint32_t T = 0u;
#pragma unroll 1
  for (int bit = 22; bit >= 0; --bit) {
    const uint32_t cand = T | (1u << bit);
    const int c = __popcll(__ballot(m[0] >= cand))
                + __popcll(__ballot(m[1] >= cand))
                + __popcll(__ballot(m[2] >= cand))
                + __popcll(__ballot(m[3] >= cand));
    if (c >= KSEL) T = cand;
  }

  uint64_t gt[4], eq[4];
#pragma unroll
  for (int g = 0; g < 4; ++g) {
    gt[g] = __ballot(m[g] > T);
    eq[g] = __ballot(m[g] == T);
  }
  eq[3] &= 0xFull;  // strip padding lanes (j >= 196)

  const int ngt = __popcll(gt[0]) + __popcll(gt[1]) + __popcll(gt[2]) + __popcll(gt[3]);
  const int need = KSEL - ngt;     // 1..eq_total
  const int e0 = __popcll(eq[0]), e1 = __popcll(eq[1]), e2 = __popcll(eq[2]);
  const uint64_t below = (1ull << lane) - 1ull;

  // take the lowest-index `need` members of the eq set
  uint64_t fin[4];
  fin[0] = gt[0] | __ballot(((eq[0] >> lane) & 1ull) &&
                            (__popcll(eq[0] & below) < need));
  fin[1] = gt[1] | __ballot(((eq[1] >> lane) & 1ull) &&
                            (e0 + __popcll(eq[1] & below) < need));
  fin[2] = gt[2] | __ballot(((eq[2] >> lane) & 1ull) &&
                            (e0 + e1 + __popcll(eq[2] & below) < need));
  fin[3] = gt[3] | __ballot(((eq[3] >> lane) & 1ull) &&
                            (e0 + e1 + e2 + __popcll(eq[3] & below) < need));

  const int c0 = __popcll(fin[0]);
  const int c1 = c0 + __popcll(fin[1]);
  const int c2 = c1 + __popcll(fin[2]);

  uint8_t* row = idxbuf + (size_t)wid * ROWSTRIDE;
  if ((fin[0] >> lane) & 1ull) row[__popcll(fin[0] & below)]      = (uint8_t)lane;
  if ((fin[1] >> lane) & 1ull) row[c0 + __popcll(fin[1] & below)] = (uint8_t)(64 + lane);
  if ((fin[2] >> lane) & 1ull) row[c1 + __popcll(fin[2] & below)] = (uint8_t)(128 + lane);
  if ((fin[3] >> lane) & 1ull) row[c2 + __popcll(fin[3] & below)] = (uint8_t)(192 + lane);
}

// B1: block = (b, rank-group of 8). 672 blocks. Each block reads bytes
// [8g, 8g+8) of every sample row (uint2, L2-resident; full rows reused by
// the 7 same-b groups), LDS-histograms 8 ranks, writes u16 counts.
// Padding bytes (rank >= 49, poison 0xAA=170 < 196) land in discarded rows.
__global__ __launch_bounds__(256)
void hist_kernel(const uint8_t* __restrict__ idxbuf,
                 uint16_t* __restrict__ cnt) {
  const int b = blockIdx.x % BF;     // b -> XCD b%8 for every group
  const int g = blockIdx.x / BF;     // 0..6, ranks [8g, 8g+8)
  const int t = threadIdx.x;

  __shared__ uint32_t hist[8 * DSP];   // 6272 B
  for (int i = t; i < 8 * DSP; i += 256) hist[i] = 0u;
  __syncthreads();

  const uint8_t* base = idxbuf + (size_t)b * NS * ROWSTRIDE + 8 * g;
  for (int r = t; r < NS; r += 256) {
    const uint2 v = *(const uint2*)(base + (size_t)r * ROWSTRIDE);
#pragma unroll
    for (int q = 0; q < 2; ++q) {
      uint32_t w = q ? v.y : v.x;
#pragma unroll
      for (int bb = 0; bb < 4; ++bb) {
        atomicAdd(&hist[(q * 4 + bb) * DSP + (w & 0xffu)], 1u);
        w >>= 8;
      }
    }
  }
  __syncthreads();

  uint16_t* cb = cnt + (size_t)b * KSEL * DSP;
  for (int i = t; i < 8 * DSP; i += 256) {
    const int rank = 8 * g + i / DSP;
    if (rank < KSEL) cb[(size_t)rank * DSP + (i % DSP)] = (uint16_t)hist[i];
  }
}

// B2: out[b,1+k,:] = (cnt[b] @ x[b,1:,:]) / NS, dense tiled, k split in two.
// Block = (b, dtile 0..7, khalf 0..1); 1536 blocks; 256 thr = 16 dt x 16 kg;
// thread tile 2k x 4d. LDS 12.5 KB -> 8 blocks/CU (32 waves, max occupancy).
// b = bid % 96 keeps all 16 blocks of one b on one XCD (96 % 8 == 0).
// k=24 is computed by both khalves from identical data (benign overlap).
__global__ __launch_bounds__(256)
void gemm_kernel(const float* __restrict__ x,
                 const uint16_t* __restrict__ cnt,
                 float* __restrict__ out) {
  const int b = blockIdx.x % BF;
  const int tmp = blockIdx.x / BF;          // 0..15
  const int dtile = tmp & 7;
  const int khalf = tmp >> 3;
  const int k0 = khalf * 24;                // rows k0 .. k0+24 (25 rows)
  const int t = threadIdx.x;
  const int dt = t & 15, kg = t >> 4;

  constexpr int JP = DSP / 2;               // 98 u16-pairs per row
  __shared__ uint32_t cfp[32 * JP];         // 12544 B, rows 25..31 zero
  const uint32_t* cp = (const uint32_t*)(cnt + (size_t)b * KSEL * DSP)
                     + (size_t)k0 * JP;
  for (int i = t; i < 25 * JP; i += 256) cfp[i] = cp[i];
  for (int i = 25 * JP + t; i < 32 * JP; i += 256) cfp[i] = 0u;
  __syncthreads();

  const float* xb = x + (size_t)b * NTOK * DIM + DIM /*skip cls*/
                  + dtile * 64 + dt * 4;
  float4 acc[2] = {};
#pragma unroll 2
  for (int j2 = 0; j2 < JP; ++j2) {
    const float4 xv0 = *(const float4*)(xb + (size_t)(2 * j2) * DIM);
    const float4 xv1 = *(const float4*)(xb + (size_t)(2 * j2 + 1) * DIM);
#pragma unroll
    for (int i = 0; i < 2; ++i) {
      const uint32_t pr = cfp[(kg + 16 * i) * JP + j2];   // 16-lane broadcast
      const float c0 = (float)(pr & 0xffffu);
      const float c1 = (float)(pr >> 16);
      acc[i].x = fmaf(c0, xv0.x, acc[i].x);
      acc[i].y = fmaf(c0, xv0.y, acc[i].y);
      acc[i].z = fmaf(c0, xv0.z, acc[i].z);
      acc[i].w = fmaf(c0, xv0.w, acc[i].w);
      acc[i].x = fmaf(c1, xv1.x, acc[i].x);
      acc[i].y = fmaf(c1, xv1.y, acc[i].y);
      acc[i].z = fmaf(c1, xv1.z, acc[i].z);
      acc[i].w = fmaf(c1, xv1.w, acc[i].w);
    }
  }

  float* ob = out + (size_t)b * (1 + KSEL) * DIM + dtile * 64 + dt * 4;
  const float inv = 1.0f / (float)NS;
#pragma unroll
  for (int i = 0; i < 2; ++i) {
    const int kl = kg + 16 * i;
    const int k = k0 + kl;
    if (kl < 25 && k < KSEL) {
      float4 r;
      r.x = acc[i].x * inv; r.y = acc[i].y * inv;
      r.z = acc[i].z * inv; r.w = acc[i].w * inv;
      *(float4*)(ob + (size_t)(1 + k) * DIM) = r;
    }
  }

  // cls row: 16 threads (kg==0) per (b, dtile) copy their 64-col slice
  if (khalf == 0 && kg == 0) {
    const float4 c4 = *(const float4*)(x + (size_t)b * NTOK * DIM
                                       + dtile * 64 + dt * 4);
    *(float4*)(ob) = c4;
  }
}

extern "C" void kernel_launch(void* const* d_in, const int* in_sizes, int n_in,
                              void* d_out, int out_size, void* d_ws, size_t ws_size,
                              hipStream_t stream) {
  const float* x = (const float*)d_in[0];
  float* out = (float*)d_out;
  uint8_t* idxbuf = (uint8_t*)d_ws;                        // 3,072,000 B
  uint16_t* cnt = (uint16_t*)((uint8_t*)d_ws +
                              (size_t)BF * NS * ROWSTRIDE); // 1,843,968 B

  topk_idx_kernel<<<dim3(BF * NS / 4), 256, 0, stream>>>(idxbuf);
  hist_kernel<<<dim3(BF * 7), 256, 0, stream>>>(idxbuf, cnt);
  gemm_kernel<<<dim3(BF * 8 * 2), 256, 0, stream>>>(x, cnt, out);
}

// Round 12
// 151.889 us; speedup vs baseline: 1.0899x; 1.0899x over previous
//
#include <hip/hip_runtime.h>
#include <stdint.h>

// jax_threefry_partitionable=True: 32-bit random bits are (out0 ^ out1) of
// threefry2x32(key, (hi32(i)=0, lo32(i)=i)), key = (0, 42).
// Ordering: JAX normal is strictly monotone in the 23 mantissa bits ->
// top-k order == mantissa order, lower-index tie-break. Verified passing
// rounds 2/4/6/10/11 (absmax 0.0112 vs threshold 0.0844).
constexpr int BF   = 96;    // B * MAX_FRAMES
constexpr int NS   = 500;   // NUM_SAMPLES
constexpr int DSP  = 196;   // N - 1 spatial tokens
constexpr int KSEL = 49;    // TOPK
constexpr int NTOK = 197;   // N
constexpr int DIM  = 512;   // D
constexpr int ROWSTRIDE = 64;   // padded byte stride of one sample's idx row

__device__ __forceinline__ uint32_t rotl32(uint32_t x, int r) {
  return __builtin_amdgcn_alignbit(x, x, 32 - r);   // one v_alignbit_b32
}

__device__ __forceinline__ void threefry2x32(uint32_t x0, uint32_t x1,
                                             uint32_t& o0, uint32_t& o1) {
  const uint32_t ks0 = 0u, ks1 = 42u, ks2 = 0u ^ 42u ^ 0x1BD11BDAu;
  x0 += ks0; x1 += ks1;
#define TF_R(r) { x0 += x1; x1 = rotl32(x1, (r)); x1 ^= x0; }
  TF_R(13) TF_R(15) TF_R(26) TF_R(6)   x0 += ks1; x1 += ks2 + 1u;
  TF_R(17) TF_R(29) TF_R(16) TF_R(24)  x0 += ks2; x1 += ks0 + 2u;
  TF_R(13) TF_R(15) TF_R(26) TF_R(6)   x0 += ks0; x1 += ks1 + 3u;
  TF_R(17) TF_R(29) TF_R(16) TF_R(24)  x0 += ks1; x1 += ks2 + 4u;
  TF_R(13) TF_R(15) TF_R(26) TF_R(6)   x0 += ks2; x1 += ks0 + 5u;
#undef TF_R
  o0 = x0; o1 = x1;
}

__device__ __forceinline__ uint32_t noise_bits(uint32_t p) {
  uint32_t o0, o1;
  threefry2x32(0u, p, o0, o1);
  return o0 ^ o1;
}

// One wave per (b, sample): top-49 of 196 mantissas (23-bit search; ties ->
// lowest index), write the 49 SORTED selected indices as bytes.
__global__ __launch_bounds__(256)
void topk_idx_kernel(uint8_t* __restrict__ idxbuf) {
  const int lane = threadIdx.x & 63;
  const int wid  = (blockIdx.x << 2) | (threadIdx.x >> 6);
  const uint32_t rowbase = (uint32_t)wid * (uint32_t)DSP;

  uint32_t m[4];
#pragma unroll
  for (int g = 0; g < 4; ++g) {
    const int j = (g << 6) | lane;
    uint32_t v = 0u;
    if (j < DSP) v = noise_bits(rowbase + (uint32_t)j) >> 9;  // 23-bit mantissa
    m[g] = v;
  }

  uint32_t T = 0u;
#pragma unroll 1
  for (int bit = 22; bit >= 0; --bit) {
    const uint32_t cand = T | (1u << bit);
    const int c = __popcll(__ballot(m[0] >= cand))
                + __popcll(__ballot(m[1] >= cand))
                + __popcll(__ballot(m[2] >= cand))
                + __popcll(__ballot(m[3] >= cand));
    if (c >= KSEL) T = cand;
  }

  uint64_t gt[4], eq[4];
#pragma unroll
  for (int g = 0; g < 4; ++g) {
    gt[g] = __ballot(m[g] > T);
    eq[g] = __ballot(m[g] == T);
  }
  eq[3] &= 0xFull;  // strip padding lanes (j >= 196)

  const int ngt = __popcll(gt[0]) + __popcll(gt[1]) + __popcll(gt[2]) + __popcll(gt[3]);
  const int need = KSEL - ngt;
  const int e0 = __popcll(eq[0]), e1 = __popcll(eq[1]), e2 = __popcll(eq[2]);
  const uint64_t below = (1ull << lane) - 1ull;

  uint64_t fin[4];
  fin[0] = gt[0] | __ballot(((eq[0] >> lane) & 1ull) &&
                            (__popcll(eq[0] & below) < need));
  fin[1] = gt[1] | __ballot(((eq[1] >> lane) & 1ull) &&
                            (e0 + __popcll(eq[1] & below) < need));
  fin[2] = gt[2] | __ballot(((eq[2] >> lane) & 1ull) &&
                            (e0 + e1 + __popcll(eq[2] & below) < need));
  fin[3] = gt[3] | __ballot(((eq[3] >> lane) & 1ull) &&
                            (e0 + e1 + e2 + __popcll(eq[3] & below) < need));

  const int c0 = __popcll(fin[0]);
  const int c1 = c0 + __popcll(fin[1]);
  const int c2 = c1 + __popcll(fin[2]);

  uint8_t* row = idxbuf + (size_t)wid * ROWSTRIDE;
  if ((fin[0] >> lane) & 1ull) row[__popcll(fin[0] & below)]      = (uint8_t)lane;
  if ((fin[1] >> lane) & 1ull) row[c0 + __popcll(fin[1] & below)] = (uint8_t)(64 + lane);
  if ((fin[2] >> lane) & 1ull) row[c1 + __popcll(fin[2] & below)] = (uint8_t)(128 + lane);
  if ((fin[3] >> lane) & 1ull) row[c2 + __popcll(fin[3] & below)] = (uint8_t)(192 + lane);
}

// B1: block = (b, rank-group of 8). 672 blocks. uint2 reads of bytes
// [8g,8g+8) per sample row; LDS histogram of 8 ranks; u16 counts out.
// Padding bytes (poison 0xAA=170 < 196) land in discarded rank>=49 rows.
__global__ __launch_bounds__(256)
void hist_kernel(const uint8_t* __restrict__ idxbuf,
                 uint16_t* __restrict__ cnt) {
  const int b = blockIdx.x % BF;
  const int g = blockIdx.x / BF;     // 0..6
  const int t = threadIdx.x;

  __shared__ uint32_t hist[8 * DSP];
  for (int i = t; i < 8 * DSP; i += 256) hist[i] = 0u;
  __syncthreads();

  const uint8_t* base = idxbuf + (size_t)b * NS * ROWSTRIDE + 8 * g;
  for (int r = t; r < NS; r += 256) {
    const uint2 v = *(const uint2*)(base + (size_t)r * ROWSTRIDE);
#pragma unroll
    for (int q = 0; q < 2; ++q) {
      uint32_t w = q ? v.y : v.x;
#pragma unroll
      for (int bb = 0; bb < 4; ++bb) {
        atomicAdd(&hist[(q * 4 + bb) * DSP + (w & 0xffu)], 1u);
        w >>= 8;
      }
    }
  }
  __syncthreads();

  uint16_t* cb = cnt + (size_t)b * KSEL * DSP;
  for (int i = t; i < 8 * DSP; i += 256) {
    const int rank = 8 * g + i / DSP;
    if (rank < KSEL) cb[(size_t)rank * DSP + (i % DSP)] = (uint16_t)hist[i];
  }
}

// B2: out[b,1+k,:] = (cnt[b] @ x[b,1:,:]) / NS.
// Block (b, 64-col dtile) = 768 blocks, 256 thr = 16 dt x 16 kg, acc 4k x 4d.
// x-tile staged in LDS in 32-row chunks (each float4 loaded ONCE per block,
// was 16x redundant), register-prefetched one chunk ahead. cnt pre-converted
// to f32 in LDS, row stride 225 (rows 16 apart -> banks 16 apart; the only
// alias is +32 rows = 2-way = free). j 196..223 computed against zeroed cf
// columns (branchless tail). b = bid % 96 -> all 8 tiles of one b on one XCD.
__global__ __launch_bounds__(256)
void gemm_kernel(const float* __restrict__ x,
                 const uint16_t* __restrict__ cnt,
                 float* __restrict__ out) {
  const int b = blockIdx.x % BF;
  const int dtile = blockIdx.x / BF;        // 0..7
  const int t = threadIdx.x;
  const int dt = t & 15, kg = t >> 4;

  constexpr int CFS = 225;                  // padded f32 row stride
  __shared__ float cf[KSEL * CFS];          // 44,100 B
  __shared__ float xl[32 * 64];             //  8,192 B

  // stage cnt -> f32 (u32 = 2 u16)
  const uint32_t* cp = (const uint32_t*)(cnt + (size_t)b * KSEL * DSP);
  for (int i = t; i < KSEL * (DSP / 2); i += 256) {
    const uint32_t v = cp[i];
    const int r = i / (DSP / 2), q = i % (DSP / 2);
    cf[r * CFS + 2 * q]     = (float)(v & 0xffffu);
    cf[r * CFS + 2 * q + 1] = (float)(v >> 16);
  }
  for (int i = t; i < KSEL * (CFS - DSP); i += 256) {   // zero pad cols
    const int r = i / (CFS - DSP), q = i % (CFS - DSP);
    cf[r * CFS + DSP + q] = 0.0f;
  }

  // x window: rows j=0..195 of spatial_feat, cols [dtile*64, +64)
  const float* xsrc = x + (size_t)b * NTOK * DIM + DIM + dtile * 64;
  const int jl = t >> 3;            // 0..31 (LDS row this thread stages)
  const int cl = (t & 7) * 8;       // col offset (2 float4s)

  float4 p0, p1;
  {   // prefetch chunk 0
    const float* s = xsrc + (size_t)jl * DIM + cl;
    p0 = *(const float4*)(s);
    p1 = *(const float4*)(s + 4);
  }

  float4 acc[4] = {};
#pragma unroll 1
  for (int c = 0; c < 7; ++c) {
    __syncthreads();               // cf ready (c=0) / prior compute done
    {   // write staged chunk (tail: jl>=4 rewrites identical chunk-5 data)
      float* d = &xl[jl * 64 + cl];
      *(float4*)(d) = p0;
      *(float4*)(d + 4) = p1;
    }
    __syncthreads();
    if (c < 6) {                   // prefetch next chunk (in flight below)
      const int nj = 32 * (c + 1);
      if (c + 1 < 6 || jl < 4) {
        const float* s = xsrc + (size_t)(nj + jl) * DIM + cl;
        p0 = *(const float4*)(s);
        p1 = *(const float4*)(s + 4);
      }
    }
    const int jb = 32 * c;
#pragma unroll 4
    for (int j = 0; j < 32; ++j) {
      const float4 xv = *(const float4*)&xl[j * 64 + dt * 4];
      const int jc = jb + j;       // cf cols >=196 are zero (tail)
      {
        const float cv = cf[kg * CFS + jc];
        acc[0].x = fmaf(cv, xv.x, acc[0].x);
        acc[0].y = fmaf(cv, xv.y, acc[0].y);
        acc[0].z = fmaf(cv, xv.z, acc[0].z);
        acc[0].w = fmaf(cv, xv.w, acc[0].w);
      }
      {
        const float cv = cf[(kg + 16) * CFS + jc];
        acc[1].x = fmaf(cv, xv.x, acc[1].x);
        acc[1].y = fmaf(cv, xv.y, acc[1].y);
        acc[1].z = fmaf(cv, xv.z, acc[1].z);
        acc[1].w = fmaf(cv, xv.w, acc[1].w);
      }
      {
        const float cv = cf[(kg + 32) * CFS + jc];
        acc[2].x = fmaf(cv, xv.x, acc[2].x);
        acc[2].y = fmaf(cv, xv.y, acc[2].y);
        acc[2].z = fmaf(cv, xv.z, acc[2].z);
        acc[2].w = fmaf(cv, xv.w, acc[2].w);
      }
      if (kg == 0) {               // row 48 (rows 49..63 don't exist)
        const float cv = cf[48 * CFS + jc];
        acc[3].x = fmaf(cv, xv.x, acc[3].x);
        acc[3].y = fmaf(cv, xv.y, acc[3].y);
        acc[3].z = fmaf(cv, xv.z, acc[3].z);
        acc[3].w = fmaf(cv, xv.w, acc[3].w);
      }
    }
  }

  float* ob = out + (size_t)b * (1 + KSEL) * DIM + dtile * 64 + dt * 4;
  const float inv = 1.0f / (float)NS;
  float4 r;
  r.x = acc[0].x * inv; r.y = acc[0].y * inv;
  r.z = acc[0].z * inv; r.w = acc[0].w * inv;
  *(float4*)(ob + (size_t)(1 + kg) * DIM) = r;
  r.x = acc[1].x * inv; r.y = acc[1].y * inv;
  r.z = acc[1].z * inv; r.w = acc[1].w * inv;
  *(float4*)(ob + (size_t)(1 + kg + 16) * DIM) = r;
  r.x = acc[2].x * inv; r.y = acc[2].y * inv;
  r.z = acc[2].z * inv; r.w = acc[2].w * inv;
  *(float4*)(ob + (size_t)(1 + kg + 32) * DIM) = r;
  if (kg == 0) {
    r.x = acc[3].x * inv; r.y = acc[3].y * inv;
    r.z = acc[3].z * inv; r.w = acc[3].w * inv;
    *(float4*)(ob + (size_t)(1 + 48) * DIM) = r;
    // cls row: 16 threads per (b, dtile) copy their 64-col slice
    const float4 c4 = *(const float4*)(x + (size_t)b * NTOK * DIM
                                       + dtile * 64 + dt * 4);
    *(float4*)(ob) = c4;
  }
}

extern "C" void kernel_launch(void* const* d_in, const int* in_sizes, int n_in,
                              void* d_out, int out_size, void* d_ws, size_t ws_size,
                              hipStream_t stream) {
  const float* x = (const float*)d_in[0];
  float* out = (float*)d_out;
  uint8_t* idxbuf = (uint8_t*)d_ws;                        // 3,072,000 B
  uint16_t* cnt = (uint16_t*)((uint8_t*)d_ws +
                              (size_t)BF * NS * ROWSTRIDE); // 1,843,968 B

  topk_idx_kernel<<<dim3(BF * NS / 4), 256, 0, stream>>>(idxbuf);
  hist_kernel<<<dim3(BF * 7), 256, 0, stream>>>(idxbuf, cnt);
  gemm_kernel<<<dim3(BF * 8), 256, 0, stream>>>(x, cnt, out);
}

// Round 14
// 143.770 us; speedup vs baseline: 1.1514x; 1.0565x over previous
//
#include <hip/hip_runtime.h>
#include <stdint.h>

// jax_threefry_partitionable=True: 32-bit random bits are (out0 ^ out1) of
// threefry2x32(key, (hi32(i)=0, lo32(i)=i)), key = (0, 42).
// Ordering note: JAX's normal = erfinv(uniform(mantissa)) is strictly
// monotone in the 23 mantissa bits, so top-k order == mantissa order with
// lower-index tie-break. Verified passing rounds 2/4/6/10/11/12 (absmax
// 0.0112 vs threshold 0.0844 = fp32 sum-order noise).
// CONFIG = r10 best-measured (146.1 us): hist96 + gemm768 u16-pair.
// Delta this round: topk threshold loop fully unrolled (was #pragma unroll 1).
constexpr int BF   = 96;    // B * MAX_FRAMES
constexpr int NS   = 500;   // NUM_SAMPLES
constexpr int DSP  = 196;   // N - 1 spatial tokens
constexpr int KSEL = 49;    // TOPK
constexpr int NTOK = 197;   // N
constexpr int DIM  = 512;   // D
constexpr int ROWSTRIDE = 64;   // padded byte stride of one sample's idx row

__device__ __forceinline__ uint32_t rotl32(uint32_t x, int r) {
  // single v_alignbit_b32: rotl(x,r) = rotr(x,32-r)
  return __builtin_amdgcn_alignbit(x, x, 32 - r);
}

__device__ __forceinline__ void threefry2x32(uint32_t x0, uint32_t x1,
                                             uint32_t& o0, uint32_t& o1) {
  const uint32_t ks0 = 0u, ks1 = 42u, ks2 = 0u ^ 42u ^ 0x1BD11BDAu;
  x0 += ks0; x1 += ks1;
#define TF_R(r) { x0 += x1; x1 = rotl32(x1, (r)); x1 ^= x0; }
  TF_R(13) TF_R(15) TF_R(26) TF_R(6)   x0 += ks1; x1 += ks2 + 1u;
  TF_R(17) TF_R(29) TF_R(16) TF_R(24)  x0 += ks2; x1 += ks0 + 2u;
  TF_R(13) TF_R(15) TF_R(26) TF_R(6)   x0 += ks0; x1 += ks1 + 3u;
  TF_R(17) TF_R(29) TF_R(16) TF_R(24)  x0 += ks1; x1 += ks2 + 4u;
  TF_R(13) TF_R(15) TF_R(26) TF_R(6)   x0 += ks2; x1 += ks0 + 5u;
#undef TF_R
  o0 = x0; o1 = x1;
}

__device__ __forceinline__ uint32_t noise_bits(uint32_t p) {
  uint32_t o0, o1;
  threefry2x32(0u, p, o0, o1);
  return o0 ^ o1;
}

// One wave per (b, sample): top-49 of 196 mantissas (23-bit search; ties ->
// lowest index), write the 49 SORTED selected indices as bytes.
__global__ __launch_bounds__(256)
void topk_idx_kernel(uint8_t* __restrict__ idxbuf) {
  const int lane = threadIdx.x & 63;
  const int wid  = (blockIdx.x << 2) | (threadIdx.x >> 6);
  const uint32_t rowbase = (uint32_t)wid * (uint32_t)DSP;

  uint32_t m[4];
#pragma unroll
  for (int g = 0; g < 4; ++g) {
    const int j = (g << 6) | lane;
    uint32_t v = 0u;
    if (j < DSP) v = noise_bits(rowbase + (uint32_t)j) >> 9;  // 23-bit mantissa
    m[g] = v;
  }

  // Largest T with count(m >= T) >= 49. cand >= 1 so padding (m=0) never
  // counts. Fully unrolled: no loop/branch overhead; only T is loop-carried.
  uint32_t T = 0u;
#pragma unroll
  for (int bit = 22; bit >= 0; --bit) {
    const uint32_t cand = T | (1u << bit);
    const int c = __popcll(__ballot(m[0] >= cand))
                + __popcll(__ballot(m[1] >= cand))
                + __popcll(__ballot(m[2] >= cand))
                + __popcll(__ballot(m[3] >= cand));
    if (c >= KSEL) T = cand;
  }

  uint64_t gt[4], eq[4];
#pragma unroll
  for (int g = 0; g < 4; ++g) {
    gt[g] = __ballot(m[g] > T);
    eq[g] = __ballot(m[g] == T);
  }
  eq[3] &= 0xFull;  // strip padding lanes (j >= 196)

  const int ngt = __popcll(gt[0]) + __popcll(gt[1]) + __popcll(gt[2]) + __popcll(gt[3]);
  const int need = KSEL - ngt;     // 1..eq_total
  const int e0 = __popcll(eq[0]), e1 = __popcll(eq[1]), e2 = __popcll(eq[2]);
  const uint64_t below = (1ull << lane) - 1ull;

  // take the lowest-index `need` members of the eq set
  uint64_t fin[4];
  fin[0] = gt[0] | __ballot(((eq[0] >> lane) & 1ull) &&
                            (__popcll(eq[0] & below) < need));
  fin[1] = gt[1] | __ballot(((eq[1] >> lane) & 1ull) &&
                            (e0 + __popcll(eq[1] & below) < need));
  fin[2] = gt[2] | __ballot(((eq[2] >> lane) & 1ull) &&
                            (e0 + e1 + __popcll(eq[2] & below) < need));
  fin[3] = gt[3] | __ballot(((eq[3] >> lane) & 1ull) &&
                            (e0 + e1 + e2 + __popcll(eq[3] & below) < need));

  const int c0 = __popcll(fin[0]);
  const int c1 = c0 + __popcll(fin[1]);
  const int c2 = c1 + __popcll(fin[2]);

  uint8_t* row = idxbuf + (size_t)wid * ROWSTRIDE;
  if ((fin[0] >> lane) & 1ull) row[__popcll(fin[0] & below)]      = (uint8_t)lane;
  if ((fin[1] >> lane) & 1ull) row[c0 + __popcll(fin[1] & below)] = (uint8_t)(64 + lane);
  if ((fin[2] >> lane) & 1ull) row[c1 + __popcll(fin[2] & below)] = (uint8_t)(128 + lane);
  if ((fin[3] >> lane) & 1ull) row[c2 + __popcll(fin[3] & below)] = (uint8_t)(192 + lane);
}

// B1: one block per b. Coalesced uint4 loads of the 49-byte rank rows ->
// LDS histogram cnt[k][j] -> u16 to ws. Also copies the cls row.
__global__ __launch_bounds__(512)
void hist_kernel(const float* __restrict__ x,
                 const uint8_t* __restrict__ idxbuf,
                 uint16_t* __restrict__ cnt,
                 float* __restrict__ out) {
  const int b = blockIdx.x;
  const int t = threadIdx.x;

  __shared__ uint32_t hist[KSEL * DSP];   // 38.4 KB
  for (int i = t; i < KSEL * DSP; i += 512) hist[i] = 0u;
  __syncthreads();

  const uint32_t* rows = (const uint32_t*)(idxbuf + (size_t)b * NS * ROWSTRIDE);
  for (int c = t; c < NS * 4; c += 512) {   // 2000 16B chunks, coalesced
    const int s = c >> 2, part = c & 3;
    const uint4 v = *(const uint4*)(rows + s * 16 + part * 4);
    if (part < 3) {
      const int kbase = part * 16;
#pragma unroll
      for (int q = 0; q < 4; ++q) {
        uint32_t w = (&v.x)[q];
#pragma unroll
        for (int bb = 0; bb < 4; ++bb) {
          atomicAdd(&hist[(kbase + q * 4 + bb) * DSP + (w & 0xffu)], 1u);
          w >>= 8;
        }
      }
    } else {
      atomicAdd(&hist[48 * DSP + (v.x & 0xffu)], 1u);   // k = 48
    }
  }
  __syncthreads();

  uint16_t* cb = cnt + (size_t)b * KSEL * DSP;
  for (int i = t; i < KSEL * DSP; i += 512) cb[i] = (uint16_t)hist[i];

  // cls row
  out[(size_t)b * (1 + KSEL) * DIM + t] = x[(size_t)b * NTOK * DIM + t];
}

// B2: out[b,1+k,:] = (cnt[b] @ x[b,1:,:]) / NS, dense tiled.
// Block = (b, 64-col tile); 256 threads = 16 dt x 16 kg; thread tile 4k x 4d.
// bid = dtile*96 + b -> all 8 tiles of one b land on the same XCD (96%8==0).
// cnt staged in LDS as u16 PAIRS (25 KB -> 6 blocks/CU); j processed
// two-at-a-time, unroll 2 -> 4 global float4 loads in flight.
__global__ __launch_bounds__(256)
void gemm_kernel(const float* __restrict__ x,
                 const uint16_t* __restrict__ cnt,
                 float* __restrict__ out) {
  const int b = blockIdx.x % BF;
  const int dtile = blockIdx.x / BF;        // 0..7
  const int t = threadIdx.x;
  const int dt = t & 15, kg = t >> 4;

  constexpr int JP = DSP / 2;               // 98 u16-pairs per row
  __shared__ uint32_t cfp[64 * JP];         // 25088 B, rows 49..63 zero
  const uint32_t* cp = (const uint32_t*)(cnt + (size_t)b * KSEL * DSP);
  for (int i = t; i < KSEL * JP; i += 256) cfp[i] = cp[i];
  for (int i = KSEL * JP + t; i < 64 * JP; i += 256) cfp[i] = 0u;
  __syncthreads();

  const float* xb = x + (size_t)b * NTOK * DIM + DIM /*skip cls*/
                  + dtile * 64 + dt * 4;
  float4 acc[4] = {};
#pragma unroll 2
  for (int j2 = 0; j2 < JP; ++j2) {
    const float4 xv0 = *(const float4*)(xb + (size_t)(2 * j2) * DIM);
    const float4 xv1 = *(const float4*)(xb + (size_t)(2 * j2 + 1) * DIM);
#pragma unroll
    for (int i = 0; i < 4; ++i) {
      const uint32_t pr = cfp[(kg + 16 * i) * JP + j2];   // 16-lane broadcast
      const float c0 = (float)(pr & 0xffffu);
      const float c1 = (float)(pr >> 16);
      acc[i].x = fmaf(c0, xv0.x, acc[i].x);
      acc[i].y = fmaf(c0, xv0.y, acc[i].y);
      acc[i].z = fmaf(c0, xv0.z, acc[i].z);
      acc[i].w = fmaf(c0, xv0.w, acc[i].w);
      acc[i].x = fmaf(c1, xv1.x, acc[i].x);
      acc[i].y = fmaf(c1, xv1.y, acc[i].y);
      acc[i].z = fmaf(c1, xv1.z, acc[i].z);
      acc[i].w = fmaf(c1, xv1.w, acc[i].w);
    }
  }

  float* ob = out + (size_t)b * (1 + KSEL) * DIM + dtile * 64 + dt * 4;
  const float inv = 1.0f / (float)NS;
#pragma unroll
  for (int i = 0; i < 4; ++i) {
    const int k = kg + 16 * i;
    if (k < KSEL) {
      float4 r;
      r.x = acc[i].x * inv; r.y = acc[i].y * inv;
      r.z = acc[i].z * inv; r.w = acc[i].w * inv;
      *(float4*)(ob + (size_t)(1 + k) * DIM) = r;
    }
  }
}

extern "C" void kernel_launch(void* const* d_in, const int* in_sizes, int n_in,
                              void* d_out, int out_size, void* d_ws, size_t ws_size,
                              hipStream_t stream) {
  const float* x = (const float*)d_in[0];
  float* out = (float*)d_out;
  uint8_t* idxbuf = (uint8_t*)d_ws;                        // 3,072,000 B
  uint16_t* cnt = (uint16_t*)((uint8_t*)d_ws +
                              (size_t)BF * NS * ROWSTRIDE); // 1,843,968 B

  topk_idx_kernel<<<dim3(BF * NS / 4), 256, 0, stream>>>(idxbuf);
  hist_kernel<<<dim3(BF), 512, 0, stream>>>(x, idxbuf, cnt, out);
  gemm_kernel<<<dim3(BF * 8), 256, 0, stream>>>(x, cnt, out);
}